// Round 3
// baseline (761.847 us; speedup 1.0000x reference)
//
#include <hip/hip_runtime.h>
#include <hip/hip_bf16.h>

typedef __bf16 bf16x8 __attribute__((ext_vector_type(8)));
typedef float f32x4 __attribute__((ext_vector_type(4)));

__device__ __forceinline__ void gload16(const void* g, void* l) {
  __builtin_amdgcn_global_load_lds(
      (const __attribute__((address_space(1))) void*)g,
      (__attribute__((address_space(3))) void*)l, 16, 0, 0);
}

__device__ __forceinline__ unsigned short f2bf(float f) {
  __hip_bfloat16 h = __float2bfloat16(f);
  union { __hip_bfloat16 h; unsigned short u; } c;
  c.h = h;
  return c.u;
}

__device__ __forceinline__ void fwht16(float v[16]) {
#pragma unroll
  for (int s = 1; s < 16; s <<= 1) {
#pragma unroll
    for (int i = 0; i < 16; i++) {
      if ((i & s) == 0) {
        float a = v[i], b = v[i | s];
        v[i] = a + b;
        v[i | s] = a - b;
      }
    }
  }
}

// ---------------- FWHT #1: h1 = bf16( fwht(x*SU) / 2048 ) ----------------
__global__ __launch_bounds__(256) void fwht1_kernel(
    const float* __restrict__ x, const float* __restrict__ SU,
    unsigned short* __restrict__ H1) {
  __shared__ float lds[256 * 17];
  const int t = threadIdx.x;
  const size_t row = blockIdx.x;
  const float* xr = x + row * 4096;
  float v[16];
#pragma unroll
  for (int n2 = 0; n2 < 16; n2++) {
    int n = n2 * 256 + t;
    v[n2] = xr[n] * SU[n];
  }
  fwht16(v);
  const int n1 = t >> 4, n0 = t & 15;
#pragma unroll
  for (int j2 = 0; j2 < 16; j2++) lds[(j2 * 16 + n1) * 17 + n0] = v[j2];
  __syncthreads();
#pragma unroll
  for (int k = 0; k < 16; k++) v[k] = lds[((t >> 4) * 16 + k) * 17 + (t & 15)];
  fwht16(v);
#pragma unroll
  for (int k = 0; k < 16; k++) lds[((t >> 4) * 16 + k) * 17 + (t & 15)] = v[k];
  __syncthreads();
#pragma unroll
  for (int k = 0; k < 16; k++) v[k] = lds[t * 17 + k];
  fwht16(v);
  const float cst = 1.0f / 2048.0f;
  union { unsigned short u[16]; uint4 q[2]; } o;
#pragma unroll
  for (int k = 0; k < 16; k++) o.u[k] = f2bf(v[k] * cst);
  uint4* dst = (uint4*)(H1 + row * 4096 + (size_t)t * 16);
  dst[0] = o.q[0];
  dst[1] = o.q[1];
}

// ---------------- W conversion: Wb[m][n] = bf16(W[m][n] * Wscale[m]) -------
__global__ __launch_bounds__(256) void convw_kernel(
    const float4* __restrict__ W4, const float* __restrict__ Wscale,
    uint2* __restrict__ Wb4, int total4, int Nq) {
  int i = blockIdx.x * 256 + threadIdx.x;
  if (i >= total4) return;
  float4 w = W4[i];
  float s = Wscale[i / Nq];
  unsigned int lo = (unsigned)f2bf(w.x * s) | ((unsigned)f2bf(w.y * s) << 16);
  unsigned int hi = (unsigned)f2bf(w.z * s) | ((unsigned)f2bf(w.w * s) << 16);
  Wb4[i] = make_uint2(lo, hi);
}

// ---------------- GEMM: 256x256 tile, BK=64, 8 waves, 8-phase schedule -----
// Template-faithful: 8/4/8/4 ds_reads per phase, staging 0/2/2/4 loads/phase,
// quarter-granularity A staging (stage strictly after last read), vmcnt(4)
// gates at P4/P8 only, double-buffered B-v0 regs (bvA/bvB), T5 setprio,
// T1 XCD swizzle. LDS 128 KiB (A,B x 2buf x 256x64 bf16).

#define BARRIER()                          \
  do {                                     \
    asm volatile("" ::: "memory");         \
    __builtin_amdgcn_s_barrier();          \
    asm volatile("" ::: "memory");         \
  } while (0)
#define GATE4() asm volatile("s_waitcnt vmcnt(4)" ::: "memory")
#define GATE8() asm volatile("s_waitcnt vmcnt(8)" ::: "memory")
#define GATE0() asm volatile("s_waitcnt vmcnt(0)" ::: "memory")

// 128-row half-tile (16KB): 2 gload16/thread. LDS dest linear; global source
// pre-swizzled so ds_read applies chunk ^= (row&7) (both-sides involution).
__device__ __forceinline__ void stage_half(const unsigned short* __restrict__ g,
                                           unsigned short* l, int tid, int K) {
#pragma unroll
  for (int i = 0; i < 2; i++) {
    int idx = i * 512 + tid;
    int r = idx >> 3;
    int c = (idx & 7) ^ (r & 7);
    gload16(g + (size_t)r * K + c * 8, l + idx * 8);
  }
}
// 64-row quarter-tile (8KB): 1 gload16/thread. (64|q*64) keeps (R&7)==(r&7).
__device__ __forceinline__ void stage_quarter(
    const unsigned short* __restrict__ g, unsigned short* l, int tid, int K) {
  int r = tid >> 3;
  int c = (tid & 7) ^ (r & 7);
  gload16(g + (size_t)r * K + c * 8, l + tid * 8);
}

#define STAGE_A(d, hh, kt) \
  stage_half(Abase + (size_t)(hh) * 128 * K + (size_t)(kt) * 64, &As[d][(hh) * 8192], tid, K)
#define STAGE_B(d, hh, kt) \
  stage_half(Bbase + (size_t)(hh) * 128 * K + (size_t)(kt) * 64, &Bs[d][(hh) * 8192], tid, K)
#define STAGE_AQ(d, q, kt) \
  stage_quarter(Abase + (size_t)(q) * 64 * K + (size_t)(kt) * 64, &As[d][(q) * 4096], tid, K)

#define LOAD_A(d, h)                                                          \
  {                                                                           \
    _Pragma("unroll") for (int i = 0; i < 4; i++) {                           \
      _Pragma("unroll") for (int ks = 0; ks < 2; ks++) {                      \
        int r = wm * 128 + (h) * 64 + i * 16 + fr;                            \
        int kc = ks * 4 + lhi;                                                \
        ah[i][ks] = *(const bf16x8*)&As[d][r * 64 + ((kc ^ (r & 7)) << 3)];   \
      }                                                                       \
    }                                                                         \
  }

#define LOAD_B(d, v, dst)                                                     \
  {                                                                           \
    _Pragma("unroll") for (int j = 0; j < 2; j++) {                           \
      _Pragma("unroll") for (int ks = 0; ks < 2; ks++) {                      \
        int r = wn * 64 + (v) * 32 + j * 16 + fr;                             \
        int kc = ks * 4 + lhi;                                                \
        dst[j][ks] = *(const bf16x8*)&Bs[d][r * 64 + ((kc ^ (r & 7)) << 3)];  \
      }                                                                       \
    }                                                                         \
  }

#define MFMA_PH(h, v, bvx)                                                    \
  {                                                                           \
    __builtin_amdgcn_s_setprio(1);                                            \
    _Pragma("unroll") for (int i = 0; i < 4; i++)                             \
      _Pragma("unroll") for (int j = 0; j < 2; j++)                           \
        _Pragma("unroll") for (int ks = 0; ks < 2; ks++)                      \
          acc[(h)*4 + i][(v)*2 + j] = __builtin_amdgcn_mfma_f32_16x16x32_bf16( \
              ah[i][ks], bvx[j][ks], acc[(h)*4 + i][(v)*2 + j], 0, 0, 0);     \
    __builtin_amdgcn_s_setprio(0);                                            \
  }

__global__ __launch_bounds__(512, 2) void gemm8_kernel(
    const unsigned short* __restrict__ A, const unsigned short* __restrict__ B,
    float* __restrict__ C, int M, int K, int NT) {
  __shared__ __align__(16) unsigned short As[2][256 * 64];
  __shared__ __align__(16) unsigned short Bs[2][256 * 64];
  const int nbn = M >> 8;
  const int cpx = gridDim.x >> 3;
  int bid = blockIdx.x;
  bid = (bid & 7) * cpx + (bid >> 3);  // XCD swizzle (grid % 8 == 0)
  const int brow = (bid / nbn) << 8;
  const int bcol = (bid % nbn) << 8;
  const int tid = threadIdx.x;
  const int lane = tid & 63;
  const int w = tid >> 6;          // 8 waves: 2 (M) x 4 (N)
  const int wm = w >> 2;           // 128 rows each
  const int wn = w & 3;            // 64 cols each
  const int fr = lane & 15;
  const int lhi = lane >> 4;

  const unsigned short* Abase = A + (size_t)brow * K;
  const unsigned short* Bbase = B + (size_t)bcol * K;

  f32x4 acc[8][4];
#pragma unroll
  for (int i = 0; i < 8; i++)
#pragma unroll
    for (int j = 0; j < 4; j++) acc[i][j] = (f32x4){0.f, 0.f, 0.f, 0.f};
  bf16x8 ah[4][2], bvA[2][2], bvB[2][2], bv1[2][2];

  // Prologue: buf0 <- tile0 (8 loads), buf1 <- tile1 (8 loads); drain buf0;
  // read bvA (tile0 B-v0).
  STAGE_A(0, 0, 0);
  STAGE_A(0, 1, 0);
  STAGE_B(0, 0, 0);
  STAGE_B(0, 1, 0);
  STAGE_A(1, 0, 1);
  STAGE_A(1, 1, 1);
  STAGE_B(1, 0, 1);
  STAGE_B(1, 1, 1);
  GATE8();  // buf0's 8 done; buf1's 8 in flight
  BARRIER();
  LOAD_B(0, 0, bvA);

  const int NTT = NT / 2;
#pragma unroll 1
  for (int t = 0; t < NTT; ++t) {
    const bool last = (t == NTT - 1);
    const int u2 = 2 * t + 2, u3 = 2 * t + 3;
    // P1: dsr A(b0,h0) [8]
    LOAD_A(0, 0);
    BARRIER();
    MFMA_PH(0, 0, bvA);
    BARRIER();
    // P2: dsr B(b0,v1) [4]; stage b0.Aq0,Aq2 <- u2
    LOAD_B(0, 1, bv1);
    if (!last) { STAGE_AQ(0, 0, u2); STAGE_AQ(0, 2, u2); }
    BARRIER();
    MFMA_PH(0, 1, bv1);
    BARRIER();
    // P3: dsr A(b0,h1) [8]; stage b0.B0 <- u2
    LOAD_A(0, 1);
    if (!last) STAGE_B(0, 0, u2);
    BARRIER();
    MFMA_PH(1, 1, bv1);
    BARRIER();
    // P4: gate (b1 fully landed); dsr B(b1,v0)->bvB [4];
    //     stage b0.B1,Aq1,Aq3 <- u2
    if (!last) { GATE4(); } else { GATE0(); }
    LOAD_B(1, 0, bvB);
    if (!last) { STAGE_B(0, 1, u2); STAGE_AQ(0, 1, u2); STAGE_AQ(0, 3, u2); }
    BARRIER();
    MFMA_PH(1, 0, bvA);
    BARRIER();
    // P5: dsr A(b1,h0) [8]
    LOAD_A(1, 0);
    BARRIER();
    MFMA_PH(0, 0, bvB);
    BARRIER();
    // P6: dsr B(b1,v1) [4]; stage b1.Aq0,Aq2 <- u3
    LOAD_B(1, 1, bv1);
    if (!last) { STAGE_AQ(1, 0, u3); STAGE_AQ(1, 2, u3); }
    BARRIER();
    MFMA_PH(0, 1, bv1);
    BARRIER();
    // P7: dsr A(b1,h1) [8]; stage b1.B0 <- u3
    LOAD_A(1, 1);
    if (!last) STAGE_B(1, 0, u3);
    BARRIER();
    MFMA_PH(1, 1, bv1);
    BARRIER();
    // P8: gate (b0 tile u2 landed); dsr B(b0,v0)->bvA [4];
    //     stage b1.B1,Aq1,Aq3 <- u3
    if (!last) {
      GATE4();
      LOAD_B(0, 0, bvA);
      STAGE_B(1, 1, u3);
      STAGE_AQ(1, 1, u3);
      STAGE_AQ(1, 3, u3);
    }
    BARRIER();
    MFMA_PH(1, 0, bvB);
    BARRIER();
  }

  // Epilogue: C/D layout col=lane&15, row=(lane>>4)*4+q  [m89-verified]
  const int crow0 = brow + wm * 128 + lhi * 4;
  const int ccol0 = bcol + wn * 64 + fr;
#pragma unroll
  for (int mi = 0; mi < 8; mi++)
#pragma unroll
    for (int nj = 0; nj < 4; nj++)
#pragma unroll
      for (int q = 0; q < 4; q++)
        C[(size_t)(crow0 + mi * 16 + q) * M + ccol0 + nj * 16] = acc[mi][nj][q];
}

// ---------------- FWHT #2 (in-place on d_out): out = fwht(Y)*0.5*SV ------
__global__ __launch_bounds__(256) void fwht2_kernel(
    float* __restrict__ Y, const float* __restrict__ SV) {
  __shared__ float lds[256 * 17];
  const int t = threadIdx.x;
  const size_t row = blockIdx.x;
  float* yr = Y + row * 4096;
  float v[16];
#pragma unroll
  for (int n2 = 0; n2 < 16; n2++) v[n2] = yr[n2 * 256 + t];
  fwht16(v);
  const int n1 = t >> 4, n0 = t & 15;
#pragma unroll
  for (int j2 = 0; j2 < 16; j2++) lds[(j2 * 16 + n1) * 17 + n0] = v[j2];
  __syncthreads();
#pragma unroll
  for (int k = 0; k < 16; k++) v[k] = lds[((t >> 4) * 16 + k) * 17 + (t & 15)];
  fwht16(v);
#pragma unroll
  for (int k = 0; k < 16; k++) lds[((t >> 4) * 16 + k) * 17 + (t & 15)] = v[k];
  __syncthreads();
#pragma unroll
  for (int k = 0; k < 16; k++) v[k] = lds[t * 17 + k];
  fwht16(v);
  float outv[16];
#pragma unroll
  for (int k = 0; k < 16; k++) outv[k] = v[k] * 0.5f * SV[(size_t)t * 16 + k];
  float4* dst = (float4*)(yr + (size_t)t * 16);
#pragma unroll
  for (int k = 0; k < 4; k++)
    dst[k] = make_float4(outv[4 * k], outv[4 * k + 1], outv[4 * k + 2],
                         outv[4 * k + 3]);
}

extern "C" void kernel_launch(void* const* d_in, const int* in_sizes, int n_in,
                              void* d_out, int out_size, void* d_ws,
                              size_t ws_size, hipStream_t stream) {
  const float* x = (const float*)d_in[0];
  const float* W = (const float*)d_in[1];
  const float* SU = (const float*)d_in[2];
  const float* SV = (const float*)d_in[3];
  const float* Wscale = (const float*)d_in[4];
  const int N = in_sizes[2];      // 4096
  const int M = in_sizes[3];      // 4096
  const int T = in_sizes[0] / N;  // 16384

  unsigned short* H1 = (unsigned short*)d_ws;
  unsigned short* Wb = H1 + (size_t)T * N;
  float* out = (float*)d_out;

  fwht1_kernel<<<T, 256, 0, stream>>>(x, SU, H1);
  const int total4 = (int)(((long)M * N) / 4);
  convw_kernel<<<(total4 + 255) / 256, 256, 0, stream>>>(
      (const float4*)W, Wscale, (uint2*)Wb, total4, N / 4);
  const int NT = N / 64;  // 64 K-tiles
  gemm8_kernel<<<(T / 256) * (M / 256), 512, 0, stream>>>(H1, Wb, out, M, N, NT);
  fwht2_kernel<<<T, 256, 0, stream>>>(out, SV);
}